// Round 9
// baseline (449.674 us; speedup 1.0000x reference)
//
#include <hip/hip_runtime.h>
#include <hip/hip_bf16.h>

// MAMBA2_2D fused kernel, round 14: round-10 structure (291us best; r13
// swizzle REVERTED — conflicts went 8M->19M, store-side patterns broken).
// New: A-fragment REGISTER PRELOAD. u is head-invariant; each wave now owns
// one t-tile (mt = w&3) and holds its 8 A-fragments (32 VGPRs) across BCdt
// + all 8 head projections -> eliminates the per-head full-smU re-read
// (~55K LDS-pipe cycles/CU on the barrier-bounded critical path).
// Wave remap: (g = w>>2: z/x half, mt = w&3); 4 ch-tiles/wave, 2-acc chains.
// B weights re-read x4 from L2/L3 (600KB resident, cheap). All other phases
// byte-identical to round 10. No inline asm (r8/r9 NaN source, banned).

#define NTH 512

typedef __attribute__((ext_vector_type(8))) short short8;
typedef __attribute__((ext_vector_type(4))) short short4v;
typedef __attribute__((ext_vector_type(4))) float floatx4;

__device__ __forceinline__ short f2bs(float v){
  __hip_bfloat16 h = __float2bfloat16(v);
  return *reinterpret_cast<short*>(&h);
}
// portable bf16 pair pack: lo -> bits[15:0], hi -> bits[31:16]
__device__ __forceinline__ unsigned int pk2(float lo, float hi){
  return (unsigned int)(unsigned short)f2bs(lo)
       | ((unsigned int)(unsigned short)f2bs(hi) << 16);
}
__device__ __forceinline__ float bs2f(short s){
  union { unsigned int u; float f; } c; c.u = ((unsigned int)(unsigned short)s) << 16; return c.f;
}
__device__ __forceinline__ float bhi(unsigned int u){
  union { unsigned int u; float f; } c; c.u = u & 0xffff0000u; return c.f;
}
__device__ __forceinline__ float blo(unsigned int u){
  union { unsigned int u; float f; } c; c.u = u << 16; return c.f;
}
__device__ __forceinline__ float silu_f(float v){
  return v * __builtin_amdgcn_rcpf(1.f + __expf(-v));
}
__device__ __forceinline__ float softplus_f(float v){
  return fmaxf(v, 0.f) + log1pf(__expf(-fabsf(v)));
}

// merged setup (r12, verified):
//   blocks [0,512)   : Wc (folded fc+out_w+norm_w, bf16) [2][256][512]
//   blocks [512,804) : in_w fp32 -> bf16 [2][1168][256] (rows 1160+ zero), 8/thread
__global__ void setup_weights(const float* __restrict__ fc_w,
                              const float* __restrict__ how, const float* __restrict__ hnw,
                              const float* __restrict__ vow, const float* __restrict__ vnw,
                              const float* __restrict__ hw, const float* __restrict__ vw,
                              __hip_bfloat16* __restrict__ Wc,
                              __hip_bfloat16* __restrict__ inw)
{
  int b = blockIdx.x;
  if (b < 512) {
    __shared__ float fs[2][256];
    int dir = b >> 8;
    int rr = b & 255;
    int o0 = (rr >> 1) * 2;
    int j = (rr & 1) * 256 + threadIdx.x;
    const float* ow = dir ? vow : how;
    const float* nw = dir ? vnw : hnw;
    int off = dir ? 0 : 512;
    const float* fr0 = fc_w + o0 * 1024 + off;
    const float* fr1 = fc_w + (o0 + 1) * 1024 + off;
    fs[0][threadIdx.x] = fr0[threadIdx.x] + fr0[256 + threadIdx.x];
    fs[1][threadIdx.x] = fr1[threadIdx.x] + fr1[256 + threadIdx.x];
    __syncthreads();
    float a00 = 0.f, a01 = 0.f, a02 = 0.f, a03 = 0.f;
    float a10 = 0.f, a11 = 0.f, a12 = 0.f, a13 = 0.f;
#pragma unroll 4
    for (int k = 0; k < 256; k += 4) {
      float w0 = ow[(k + 0) * 512 + j];
      float w1 = ow[(k + 1) * 512 + j];
      float w2 = ow[(k + 2) * 512 + j];
      float w3 = ow[(k + 3) * 512 + j];
      a00 += fs[0][k + 0] * w0; a01 += fs[0][k + 1] * w1;
      a02 += fs[0][k + 2] * w2; a03 += fs[0][k + 3] * w3;
      a10 += fs[1][k + 0] * w0; a11 += fs[1][k + 1] * w1;
      a12 += fs[1][k + 2] * w2; a13 += fs[1][k + 3] * w3;
    }
    float nwj = nw[j];
    Wc[(dir * 256 + o0) * 512 + j]     = __float2bfloat16(nwj * (a00 + a01 + a02 + a03));
    Wc[(dir * 256 + o0 + 1) * 512 + j] = __float2bfloat16(nwj * (a10 + a11 + a12 + a13));
  } else {
    int id8 = ((b - 512) * 256 + threadIdx.x) * 8;  // 292 blocks -> 598016 elems
    int dir = id8 / 299008;
    int r = id8 % 299008;
    int row = r >> 8;                 // same row for all 8 elems (8 | 256)
    const float* src = dir ? vw : hw;
    short8 o;
    if (row < 1160) {
      const float4 x0 = *(const float4*)(src + r);
      const float4 x1 = *(const float4*)(src + r + 4);
      o[0] = f2bs(x0.x); o[1] = f2bs(x0.y); o[2] = f2bs(x0.z); o[3] = f2bs(x0.w);
      o[4] = f2bs(x1.x); o[5] = f2bs(x1.y); o[6] = f2bs(x1.z); o[7] = f2bs(x1.w);
    } else {
      o = (short8)0;
    }
    *(short8*)((short*)inw + id8) = o;
  }
}

// LDS short-offsets (total 36624 shorts = 73248 B -> 2 blocks/CU)
#define OFS_U    0       // bf16 [64][264] staged u; pad dword cols 128/129 hold SSQ/RMS fp32
#define OFS_R1   16896   // bf16 [136][66]: BCdt [ch][t]; head loop z rows 0..63, x rows 64..127
#define OFS_BX0  25872   // bf16 [64][72]: B[s][n] -> M[t][s] -> g[t][j]
#define OFS_BX1  30480   // bf16 [64][72]: C[t][n] -> X[p][s]
#define OFS_CUM  35088   // fp32 [8][64]
#define OFS_DT   36112   // bf16 [8][64]
#define SM_SHORTS 36624

template<int DIR>
__global__ __launch_bounds__(NTH, 4)
void mamba_dir_kernel(const float* __restrict__ x,
                      const __hip_bfloat16* __restrict__ inw_bf,  // [1168][256]
                      const float* __restrict__ conv_w,
                      const float* __restrict__ conv_b,
                      const float* __restrict__ dt_bias,
                      const float* __restrict__ A_log,
                      const float* __restrict__ Dvec,
                      const __hip_bfloat16* __restrict__ Wc,      // [256][512]
                      const float* __restrict__ fc_b,
                      float* __restrict__ out)
{
  __shared__ short sm[SM_SHORTS];
  short* smU  = sm + OFS_U;
  short* smR1 = sm + OFS_R1;
  short* smB  = sm + OFS_BX0;   // aliases smM, smg
  short* smM  = smB;
  short* smg  = smB;
  short* smC  = sm + OFS_BX1;   // aliases smX
  short* smX  = smC;
  float* smCUM = (float*)(sm + OFS_CUM);
  short* smDT  = sm + OFS_DT;
  float* smF   = (float*)sm;    // SSQ at [t*132+128], RMS at [t*132+129] (smU pad)

  const int tid = threadIdx.x;
  const int t = tid & 63;
  const int w = tid >> 6;
  const int lane15 = tid & 15;
  const int quad = (tid & 63) >> 4;
  const int s = blockIdx.x;

  auto MF = [](short8 a, short8 b, floatx4 c) -> floatx4 {
    return __builtin_amdgcn_mfma_f32_16x16x32_bf16(a, b, c, 0, 0, 0);
  };
  auto ldB_w = [&](int row0, int kt) -> short8 {
    return *(const short8*)((const short*)inw_bf + (row0 + lane15) * 256 + kt * 32 + quad * 8);
  };
  auto ldB_wc = [&](int o0, int hd, int kt) -> short8 {
    return *(const short8*)((const short*)Wc + (o0 + lane15) * 512 + hd * 64 + kt * 32 + quad * 8);
  };
  auto ld72 = [&](const short* base, int row, int kt) -> short8 {
    return *(const short8*)(base + row * 72 + kt * 32 + quad * 8);
  };

  long ubase; int ustride;
  if (DIR == 0) { ubase = (long)s * 16384; ustride = 256; }
  else { ubase = (long)(s >> 6) * 1048576 + (long)(s & 63) * 256; ustride = 16384; }

  // ---- stage u -> bf16 [t][264]: float4 loads, packed uint2 LDS writes ----
  for (int i = tid; i < 4096; i += NTH) {
    int tt = i >> 6, c4 = (i & 63) * 4;
    const float4 xa = *(const float4*)(x + ubase + (long)tt * ustride + c4);
    uint2 pk; pk.x = pk2(xa.x, xa.y); pk.y = pk2(xa.z, xa.w);
    *(uint2*)((unsigned int*)smU + tt * 132 + (i & 63) * 2) = pk;
  }
  if (tid < 64) smF[tid * 132 + 128] = 0.f;   // SSQ
  __syncthreads();

  // ---- A-fragment register preload: wave owns t-tile amt = w&3 (head-invariant) ----
  const int amt = w & 3;        // my t-tile (rows amt*16 .. amt*16+15)
  const int g   = w >> 2;       // ch-group: 0 = first half (z), 1 = second (x)
  short8 av[8];
#pragma unroll
  for (int kt = 0; kt < 8; ++kt)
    av[kt] = *(const short8*)(smU + (amt * 16 + lane15) * 264 + kt * 32 + quad * 8);

  // C-store for one 16x16 tile at (ch-row q0.., t-col amt*16): paired bf16
  auto storeC = [&](floatx4 a, int q) {
    short* dst = smR1 + q * 66 + amt * 16 + quad * 4;
    *(unsigned int*)(dst + 0) = pk2(a[0], a[1]);
    *(unsigned int*)(dst + 2) = pk2(a[2], a[3]);
  };

  // ---- BCdt projection (in_w rows 1024..1167): g=0 -> c {0,2,4,6,8}, g=1 -> {1,3,5,7} ----
  for (int c = g; c < 9; c += 2) {
    floatx4 acc = (floatx4)0.f;
#pragma unroll
    for (int kt = 0; kt < 8; ++kt)
      acc = MF(av[kt], ldB_w(1024 + c * 16, kt), acc);
    int q = c * 16 + lane15;
    if (q < 136) storeC(acc, q);
  }
  __syncthreads();

  // ---- conv+silu B/C (aligned b32 tap loads); dt softplus + cum scan (r10) ----
  {
    int q = tid & 127;            // channel 0..127 (wave-uniform B/C split)
    int tg = tid >> 7;            // 0..3
    const float4 cw = *(const float4*)(conv_w + (512 + q) * 4);
    float cb = conv_b[512 + q];
    const short* rowp = smR1 + q * 66;
    short* dstB = (q < 64) ? (smB + q) : (smC + (q - 64));
#pragma unroll
    for (int k = 0; k < 4; ++k) {
      int t0 = tg * 4 + k;        // output group: t = 4*t0 .. 4*t0+3
      const short* bp = rowp + 4 * t0 - 4;
      unsigned int u0 = *(const unsigned int*)(bp + 0);
      unsigned int u1 = *(const unsigned int*)(bp + 2);
      unsigned int u2 = *(const unsigned int*)(bp + 4);
      unsigned int u3 = *(const unsigned int*)(bp + 6);
      float f1 = bhi(u0), f2 = blo(u1), f3 = bhi(u1), f4 = blo(u2);
      float f5 = bhi(u2), f6 = blo(u3), f7 = bhi(u3);
      if (t0 == 0) { f1 = 0.f; f2 = 0.f; f3 = 0.f; }
      float v0 = fmaf(cw.x, f1, fmaf(cw.y, f2, fmaf(cw.z, f3, fmaf(cw.w, f4, cb))));
      float v1 = fmaf(cw.x, f2, fmaf(cw.y, f3, fmaf(cw.z, f4, fmaf(cw.w, f5, cb))));
      float v2 = fmaf(cw.x, f3, fmaf(cw.y, f4, fmaf(cw.z, f5, fmaf(cw.w, f6, cb))));
      float v3 = fmaf(cw.x, f4, fmaf(cw.y, f5, fmaf(cw.z, f6, fmaf(cw.w, f7, cb))));
      int tt = 4 * t0;
      dstB[(tt + 0) * 72] = f2bs(silu_f(v0));
      dstB[(tt + 1) * 72] = f2bs(silu_f(v1));
      dstB[(tt + 2) * 72] = f2bs(silu_f(v2));
      dstB[(tt + 3) * 72] = f2bs(silu_f(v3));
    }
    float dtv = softplus_f(bs2f(smR1[(128 + w) * 66 + t]) + dt_bias[w]);
    smDT[w * 64 + t] = f2bs(dtv);
    float cum = -__expf(A_log[w]) * dtv;
#pragma unroll
    for (int off = 1; off < 64; off <<= 1) {
      float y = __shfl_up(cum, off, 64);
      if (t >= off) cum += y;
    }
    smCUM[w * 64 + t] = cum;
  }
  __syncthreads();

  // ---- G = C B^T via MFMA -> REGISTERS (head-independent) ----
  const int mt = w >> 1, nt0 = (w & 1) * 2;
  floatx4 g0 = (floatx4)0.f, g1 = (floatx4)0.f;
#pragma unroll
  for (int kt = 0; kt < 2; ++kt) {
    short8 a  = ld72(smC, mt * 16 + lane15, kt);
    short8 b0 = ld72(smB, nt0 * 16 + lane15, kt);
    short8 b1 = ld72(smB, (nt0 + 1) * 16 + lane15, kt);
    g0 = MF(a, b0, g0); g1 = MF(a, b1, g1);
  }
  // smB/smC reads complete before the post-P1 barrier of head 0 -> safe vs P2 writes

  float ssqAcc = 0.f;
  floatx4 accO[4][2];
#pragma unroll
  for (int m = 0; m < 4; ++m) { accO[m][0] = (floatx4)0.f; accO[m][1] = (floatx4)0.f; }

  for (int hd = 0; hd < 8; ++hd) {
    // P1: z/x head proj from register A; wave (g, amt): 4 ch-tiles, 2-acc chains
    {
      int wb = g ? (512 + hd * 64) : (hd * 64);   // weight row base
      int qb = g * 64;                            // smR1 row base (z: 0, x: 64)
#pragma unroll
      for (int jp = 0; jp < 2; ++jp) {
        int r0 = wb + (jp * 2) * 16, r1 = wb + (jp * 2 + 1) * 16;
        floatx4 A0 = (floatx4)0.f, A1 = (floatx4)0.f;
#pragma unroll
        for (int kt = 0; kt < 8; ++kt) {
          short8 b0 = ldB_w(r0, kt);
          short8 b1 = ldB_w(r1, kt);
          A0 = MF(av[kt], b0, A0);
          A1 = MF(av[kt], b1, A1);
        }
        storeC(A0, qb + (jp * 2) * 16 + lane15);
        storeC(A1, qb + (jp * 2 + 1) * 16 + lane15);
      }
    }
    __syncthreads();

    // P2: conv+silu x -> smX bf16 [p][s] (r10); M built from G regs -> smM [t][s]
    {
      int p = t;                   // channel 0..63
      int ch = hd * 64 + p;
      const float4 cw = *(const float4*)(conv_w + ch * 4);
      float cb = conv_b[ch];
      const short* rowp = smR1 + (64 + p) * 66;
      short* dstX = smX + p * 72;
#pragma unroll
      for (int k = 0; k < 2; ++k) {
        int t0 = w * 2 + k;
        const short* bp = rowp + 4 * t0 - 4;
        unsigned int u0 = *(const unsigned int*)(bp + 0);
        unsigned int u1 = *(const unsigned int*)(bp + 2);
        unsigned int u2 = *(const unsigned int*)(bp + 4);
        unsigned int u3 = *(const unsigned int*)(bp + 6);
        float f1 = bhi(u0), f2 = blo(u1), f3 = bhi(u1), f4 = blo(u2);
        float f5 = bhi(u2), f6 = blo(u3), f7 = bhi(u3);
        if (t0 == 0) { f1 = 0.f; f2 = 0.f; f3 = 0.f; }
        float v0 = fmaf(cw.x, f1, fmaf(cw.y, f2, fmaf(cw.z, f3, fmaf(cw.w, f4, cb))));
        float v1 = fmaf(cw.x, f2, fmaf(cw.y, f3, fmaf(cw.z, f4, fmaf(cw.w, f5, cb))));
        float v2 = fmaf(cw.x, f3, fmaf(cw.y, f4, fmaf(cw.z, f5, fmaf(cw.w, f6, cb))));
        float v3 = fmaf(cw.x, f4, fmaf(cw.y, f5, fmaf(cw.z, f6, fmaf(cw.w, f7, cb))));
        *(unsigned int*)(dstX + 4 * t0)     = pk2(silu_f(v0), silu_f(v1));
        *(unsigned int*)(dstX + 4 * t0 + 2) = pk2(silu_f(v2), silu_f(v3));
      }
      const float* cumh = smCUM + hd * 64;
      const short* dth  = smDT + hd * 64;
#pragma unroll
      for (int j = 0; j < 2; ++j) {
        floatx4 gv = j ? g1 : g0;
        int ss = (nt0 + j) * 16 + lane15;
        float cums = cumh[ss];
        float dts  = bs2f(dth[ss]);
#pragma unroll
        for (int r = 0; r < 4; ++r) {
          int tt = mt * 16 + quad * 4 + r;
          float m = (tt >= ss) ? __expf(cumh[tt] - cums) * dts * gv[r] : 0.f;
          smM[tt * 72 + ss] = f2bs(m);
        }
      }
    }
    __syncthreads();

    // P3: Y = M X via MFMA (results stay in regs)
    floatx4 y0 = (floatx4)0.f, y1 = (floatx4)0.f;
#pragma unroll
    for (int kt = 0; kt < 2; ++kt) {
      short8 a  = ld72(smM, mt * 16 + lane15, kt);
      short8 b0 = ld72(smX, nt0 * 16 + lane15, kt);
      short8 b1 = ld72(smX, (nt0 + 1) * 16 + lane15, kt);
      y0 = MF(a, b0, y0); y1 = MF(a, b1, y1);
    }
    __syncthreads();   // all M reads done before g overwrites the M buffer

    // P4: D-term + silu(z) gating -> g[t][j] into the M buffer
    {
      float Dh = Dvec[hd];
#pragma unroll
      for (int j = 0; j < 2; ++j) {
        floatx4 yy = j ? y1 : y0;
        int p = (nt0 + j) * 16 + lane15;
        short4v xv4 = *(const short4v*)(smX + p * 72 + mt * 16 + quad * 4);
#pragma unroll
        for (int r = 0; r < 4; ++r) {
          int tr = mt * 16 + quad * 4 + r;
          float xv = bs2f(xv4[r]);
          float zv = bs2f(smR1[p * 66 + tr]);
          float g = (yy[r] + Dh * xv) * silu_f(zv);
          smg[tr * 72 + p] = f2bs(g);
        }
      }
    }
    __syncthreads();

    // P5: ssq into register accumulator + out-proj MFMA (g x Wc)
    {
      short8 gv = *(const short8*)(smg + t * 72 + w * 8);
#pragma unroll
      for (int j = 0; j < 8; ++j) { float g = bs2f(gv[j]); ssqAcc += g * g; }
    }
#pragma unroll
    for (int kt = 0; kt < 2; ++kt) {
      short8 b0 = ldB_wc(w * 16, hd, kt);
      short8 b1 = ldB_wc((w + 8) * 16, hd, kt);
#pragma unroll
      for (int m = 0; m < 4; ++m) {
        short8 a = ld72(smg, m * 16 + lane15, kt);
        accO[m][0] = MF(a, b0, accO[m][0]);
        accO[m][1] = MF(a, b1, accO[m][1]);
      }
    }
    // post-P1 barrier of next head guards P2's smM/smX writes vs this P5's reads
  }

  atomicAdd(&smF[t * 132 + 128], ssqAcc);
  __syncthreads();
  if (tid < 64)
    smF[tid * 132 + 129] = rsqrtf(smF[tid * 132 + 128] * (1.f / 512.f) + 1e-5f);
  __syncthreads();

  // ---- epilogue: RMS scale, direct C-layout global writes ----
#pragma unroll
  for (int m = 0; m < 4; ++m) {
#pragma unroll
    for (int n = 0; n < 2; ++n) {
      int o = (w + n * 8) * 16 + lane15;
#pragma unroll
      for (int r = 0; r < 4; ++r) {
        int tt = m * 16 + quad * 4 + r;
        float val = accO[m][n][r] * smF[tt * 132 + 129];
        long rowg = (DIR == 0) ? ((long)s * 64 + tt)
                               : ((long)(s >> 6) * 4096 + (long)tt * 64 + (s & 63));
        long gi = rowg * 256 + o;
        if (DIR == 0) out[gi] = fc_b[o] + val;
        else          out[gi] += val;
      }
    }
  }
}

extern "C" void kernel_launch(void* const* d_in, const int* in_sizes, int n_in,
                              void* d_out, int out_size, void* d_ws, size_t ws_size,
                              hipStream_t stream) {
  const float* x          = (const float*)d_in[0];
  const float* mh_in_w    = (const float*)d_in[1];
  const float* mh_conv_w  = (const float*)d_in[2];
  const float* mh_conv_b  = (const float*)d_in[3];
  const float* mh_dt_bias = (const float*)d_in[4];
  const float* mh_A_log   = (const float*)d_in[5];
  const float* mh_D       = (const float*)d_in[6];
  const float* mh_norm_w  = (const float*)d_in[7];
  const float* mh_out_w   = (const float*)d_in[8];
  const float* mv_in_w    = (const float*)d_in[9];
  const float* mv_conv_w  = (const float*)d_in[10];
  const float* mv_conv_b  = (const float*)d_in[11];
  const float* mv_dt_bias = (const float*)d_in[12];
  const float* mv_A_log   = (const float*)d_in[13];
  const float* mv_D       = (const float*)d_in[14];
  const float* mv_norm_w  = (const float*)d_in[15];
  const float* mv_out_w   = (const float*)d_in[16];
  const float* fc_w       = (const float*)d_in[17];
  const float* fc_b       = (const float*)d_in[18];
  float* out = (float*)d_out;

  __hip_bfloat16* Wcb  = (__hip_bfloat16*)d_ws;                       // 2*131072 bf16
  __hip_bfloat16* inwb = (__hip_bfloat16*)((char*)d_ws + 524288);     // 2*1168*256 bf16

  setup_weights<<<804, 256, 0, stream>>>(fc_w, mh_out_w, mh_norm_w, mv_out_w, mv_norm_w,
                                         mh_in_w, mv_in_w, Wcb, inwb);
  mamba_dir_kernel<0><<<512, NTH, 0, stream>>>(x, inwb, mh_conv_w, mh_conv_b,
      mh_dt_bias, mh_A_log, mh_D, Wcb, fc_b, out);
  mamba_dir_kernel<1><<<512, NTH, 0, stream>>>(x, inwb + 299008, mv_conv_w, mv_conv_b,
      mv_dt_bias, mv_A_log, mv_D, Wcb + 131072, fc_b, out);
}

// Round 10
// 257.828 us; speedup vs baseline: 1.7441x; 1.7441x over previous
//
#include <hip/hip_runtime.h>
#include <hip/hip_bf16.h>

// MAMBA2_2D fused kernel, round 15: round-10 base (291us best) — r14's
// A-register-preload REVERTED (broke P1's load/MFMA latency structure:
// 32 shallow-chained global loads vs r10's 8 loads x 4-deep chains ->
// 179us mains). Two low-risk levers on the r10 shape:
//  (1) pk2 via __float22bfloat162_rn (HW v_cvt_pk_bf16_f32 through the
//      standard HIP intrinsic, NOT inline asm) — removes software-RNE VALU
//      if present, no-op if compiler already fuses.
//  (2) s_setprio(1) around MFMA clusters (proj K-loop, P5 out-proj): with
//      2 independent blocks/CU at different phases, MFMA waves win issue
//      arbitration over the co-resident block's conv/VALU waves (T5).
// Setup: r12's vectorized version (verified r12/r13/r14).

#define NTH 512

typedef __attribute__((ext_vector_type(8))) short short8;
typedef __attribute__((ext_vector_type(4))) short short4v;
typedef __attribute__((ext_vector_type(4))) float floatx4;

__device__ __forceinline__ short f2bs(float v){
  __hip_bfloat16 h = __float2bfloat16(v);
  return *reinterpret_cast<short*>(&h);
}
// packed bf16 pair: lo -> bits[15:0], hi -> bits[31:16], via HW packed cvt
__device__ __forceinline__ unsigned int pk2(float lo, float hi){
  float2 f; f.x = lo; f.y = hi;
  __hip_bfloat162 b = __float22bfloat162_rn(f);
  union { __hip_bfloat162 b; unsigned int u; } c; c.b = b;
  return c.u;
}
__device__ __forceinline__ float bs2f(short s){
  union { unsigned int u; float f; } c; c.u = ((unsigned int)(unsigned short)s) << 16; return c.f;
}
__device__ __forceinline__ float bhi(unsigned int u){
  union { unsigned int u; float f; } c; c.u = u & 0xffff0000u; return c.f;
}
__device__ __forceinline__ float blo(unsigned int u){
  union { unsigned int u; float f; } c; c.u = u << 16; return c.f;
}
__device__ __forceinline__ float silu_f(float v){
  return v * __builtin_amdgcn_rcpf(1.f + __expf(-v));
}
__device__ __forceinline__ float softplus_f(float v){
  return fmaxf(v, 0.f) + log1pf(__expf(-fabsf(v)));
}

// merged setup (r12, verified):
//   blocks [0,512)   : Wc (folded fc+out_w+norm_w, bf16) [2][256][512]
//   blocks [512,804) : in_w fp32 -> bf16 [2][1168][256] (rows 1160+ zero), 8/thread
__global__ void setup_weights(const float* __restrict__ fc_w,
                              const float* __restrict__ how, const float* __restrict__ hnw,
                              const float* __restrict__ vow, const float* __restrict__ vnw,
                              const float* __restrict__ hw, const float* __restrict__ vw,
                              __hip_bfloat16* __restrict__ Wc,
                              __hip_bfloat16* __restrict__ inw)
{
  int b = blockIdx.x;
  if (b < 512) {
    __shared__ float fs[2][256];
    int dir = b >> 8;
    int rr = b & 255;
    int o0 = (rr >> 1) * 2;
    int j = (rr & 1) * 256 + threadIdx.x;
    const float* ow = dir ? vow : how;
    const float* nw = dir ? vnw : hnw;
    int off = dir ? 0 : 512;
    const float* fr0 = fc_w + o0 * 1024 + off;
    const float* fr1 = fc_w + (o0 + 1) * 1024 + off;
    fs[0][threadIdx.x] = fr0[threadIdx.x] + fr0[256 + threadIdx.x];
    fs[1][threadIdx.x] = fr1[threadIdx.x] + fr1[256 + threadIdx.x];
    __syncthreads();
    float a00 = 0.f, a01 = 0.f, a02 = 0.f, a03 = 0.f;
    float a10 = 0.f, a11 = 0.f, a12 = 0.f, a13 = 0.f;
#pragma unroll 4
    for (int k = 0; k < 256; k += 4) {
      float w0 = ow[(k + 0) * 512 + j];
      float w1 = ow[(k + 1) * 512 + j];
      float w2 = ow[(k + 2) * 512 + j];
      float w3 = ow[(k + 3) * 512 + j];
      a00 += fs[0][k + 0] * w0; a01 += fs[0][k + 1] * w1;
      a02 += fs[0][k + 2] * w2; a03 += fs[0][k + 3] * w3;
      a10 += fs[1][k + 0] * w0; a11 += fs[1][k + 1] * w1;
      a12 += fs[1][k + 2] * w2; a13 += fs[1][k + 3] * w3;
    }
    float nwj = nw[j];
    Wc[(dir * 256 + o0) * 512 + j]     = __float2bfloat16(nwj * (a00 + a01 + a02 + a03));
    Wc[(dir * 256 + o0 + 1) * 512 + j] = __float2bfloat16(nwj * (a10 + a11 + a12 + a13));
  } else {
    int id8 = ((b - 512) * 256 + threadIdx.x) * 8;  // 292 blocks -> 598016 elems
    int dir = id8 / 299008;
    int r = id8 % 299008;
    int row = r >> 8;                 // same row for all 8 elems (8 | 256)
    const float* src = dir ? vw : hw;
    short8 o;
    if (row < 1160) {
      const float4 x0 = *(const float4*)(src + r);
      const float4 x1 = *(const float4*)(src + r + 4);
      o[0] = f2bs(x0.x); o[1] = f2bs(x0.y); o[2] = f2bs(x0.z); o[3] = f2bs(x0.w);
      o[4] = f2bs(x1.x); o[5] = f2bs(x1.y); o[6] = f2bs(x1.z); o[7] = f2bs(x1.w);
    } else {
      o = (short8)0;
    }
    *(short8*)((short*)inw + id8) = o;
  }
}

// LDS short-offsets (total 36624 shorts = 73248 B -> 2 blocks/CU)
#define OFS_U    0       // bf16 [64][264] staged u; pad dword cols 128/129 hold SSQ/RMS fp32
#define OFS_R1   16896   // bf16 [136][66]: BCdt [ch][t]; head loop z rows 0..63, x rows 64..127
#define OFS_BX0  25872   // bf16 [64][72]: B[s][n] -> M[t][s] -> g[t][j]
#define OFS_BX1  30480   // bf16 [64][72]: C[t][n] -> X[p][s]
#define OFS_CUM  35088   // fp32 [8][64]
#define OFS_DT   36112   // bf16 [8][64]
#define SM_SHORTS 36624

template<int DIR>
__global__ __launch_bounds__(NTH, 4)
void mamba_dir_kernel(const float* __restrict__ x,
                      const __hip_bfloat16* __restrict__ inw_bf,  // [1168][256]
                      const float* __restrict__ conv_w,
                      const float* __restrict__ conv_b,
                      const float* __restrict__ dt_bias,
                      const float* __restrict__ A_log,
                      const float* __restrict__ Dvec,
                      const __hip_bfloat16* __restrict__ Wc,      // [256][512]
                      const float* __restrict__ fc_b,
                      float* __restrict__ out)
{
  __shared__ short sm[SM_SHORTS];
  short* smU  = sm + OFS_U;
  short* smR1 = sm + OFS_R1;
  short* smB  = sm + OFS_BX0;   // aliases smM, smg
  short* smM  = smB;
  short* smg  = smB;
  short* smC  = sm + OFS_BX1;   // aliases smX
  short* smX  = smC;
  float* smCUM = (float*)(sm + OFS_CUM);
  short* smDT  = sm + OFS_DT;
  float* smF   = (float*)sm;    // SSQ at [t*132+128], RMS at [t*132+129] (smU pad)

  const int tid = threadIdx.x;
  const int t = tid & 63;
  const int w = tid >> 6;
  const int lane15 = tid & 15;
  const int quad = (tid & 63) >> 4;
  const int s = blockIdx.x;

  auto MF = [](short8 a, short8 b, floatx4 c) -> floatx4 {
    return __builtin_amdgcn_mfma_f32_16x16x32_bf16(a, b, c, 0, 0, 0);
  };
  auto ldA_u = [&](int mt_, int kt) -> short8 {
    return *(const short8*)(smU + (mt_ * 16 + lane15) * 264 + kt * 32 + quad * 8);
  };
  auto ldB_w = [&](int row0, int kt) -> short8 {
    return *(const short8*)((const short*)inw_bf + (row0 + lane15) * 256 + kt * 32 + quad * 8);
  };
  auto ldB_wc = [&](int o0, int hd, int kt) -> short8 {
    return *(const short8*)((const short*)Wc + (o0 + lane15) * 512 + hd * 64 + kt * 32 + quad * 8);
  };
  auto ld72 = [&](const short* base, int row, int kt) -> short8 {
    return *(const short8*)(base + row * 72 + kt * 32 + quad * 8);
  };
  // 16x16 proj tile: paired bf16 stores (4B-aligned, stride 66); MFMA cluster
  // wrapped in setprio(1) — co-resident block's VALU phases yield issue slots.
  auto proj_tile = [&](int row0, short* dst, bool wr) {
    floatx4 a0 = (floatx4)0.f, a1 = (floatx4)0.f, a2 = (floatx4)0.f, a3 = (floatx4)0.f;
    __builtin_amdgcn_s_setprio(1);
#pragma unroll
    for (int kt = 0; kt < 8; ++kt) {
      short8 b = ldB_w(row0, kt);
      a0 = MF(ldA_u(0, kt), b, a0);
      a1 = MF(ldA_u(1, kt), b, a1);
      a2 = MF(ldA_u(2, kt), b, a2);
      a3 = MF(ldA_u(3, kt), b, a3);
    }
    __builtin_amdgcn_s_setprio(0);
    if (wr) {
      *(unsigned int*)(dst + 0)  = pk2(a0[0], a0[1]);
      *(unsigned int*)(dst + 2)  = pk2(a0[2], a0[3]);
      *(unsigned int*)(dst + 16) = pk2(a1[0], a1[1]);
      *(unsigned int*)(dst + 18) = pk2(a1[2], a1[3]);
      *(unsigned int*)(dst + 32) = pk2(a2[0], a2[1]);
      *(unsigned int*)(dst + 34) = pk2(a2[2], a2[3]);
      *(unsigned int*)(dst + 48) = pk2(a3[0], a3[1]);
      *(unsigned int*)(dst + 50) = pk2(a3[2], a3[3]);
    }
  };

  long ubase; int ustride;
  if (DIR == 0) { ubase = (long)s * 16384; ustride = 256; }
  else { ubase = (long)(s >> 6) * 1048576 + (long)(s & 63) * 256; ustride = 16384; }

  // ---- stage u -> bf16 [t][264]: float4 loads, packed uint2 LDS writes ----
  for (int i = tid; i < 4096; i += NTH) {
    int tt = i >> 6, c4 = (i & 63) * 4;
    const float4 xa = *(const float4*)(x + ubase + (long)tt * ustride + c4);
    uint2 pk; pk.x = pk2(xa.x, xa.y); pk.y = pk2(xa.z, xa.w);
    *(uint2*)((unsigned int*)smU + tt * 132 + (i & 63) * 2) = pk;
  }
  if (tid < 64) smF[tid * 132 + 128] = 0.f;   // SSQ
  __syncthreads();

  // ---- BCdt projection (in_w rows 1024..1167, 9 n-tiles) -> smR1 bf16 [136][66] ----
  for (int jt = w; jt < 9; jt += 8) {
    int q = jt * 16 + lane15;
    proj_tile(1024 + jt * 16, smR1 + q * 66 + quad * 4, q < 136);
  }
  __syncthreads();

  // ---- conv+silu B/C (aligned b32 tap loads); dt softplus + cum scan ----
  {
    int q = tid & 127;            // channel 0..127 (wave-uniform B/C split)
    int tg = tid >> 7;            // 0..3
    const float4 cw = *(const float4*)(conv_w + (512 + q) * 4);
    float cb = conv_b[512 + q];
    const short* rowp = smR1 + q * 66;
    short* dstB = (q < 64) ? (smB + q) : (smC + (q - 64));
#pragma unroll
    for (int k = 0; k < 4; ++k) {
      int t0 = tg * 4 + k;        // output group: t = 4*t0 .. 4*t0+3
      const short* bp = rowp + 4 * t0 - 4;
      unsigned int u0 = *(const unsigned int*)(bp + 0);
      unsigned int u1 = *(const unsigned int*)(bp + 2);
      unsigned int u2 = *(const unsigned int*)(bp + 4);
      unsigned int u3 = *(const unsigned int*)(bp + 6);
      float f1 = bhi(u0), f2 = blo(u1), f3 = bhi(u1), f4 = blo(u2);
      float f5 = bhi(u2), f6 = blo(u3), f7 = bhi(u3);
      if (t0 == 0) { f1 = 0.f; f2 = 0.f; f3 = 0.f; }
      float v0 = fmaf(cw.x, f1, fmaf(cw.y, f2, fmaf(cw.z, f3, fmaf(cw.w, f4, cb))));
      float v1 = fmaf(cw.x, f2, fmaf(cw.y, f3, fmaf(cw.z, f4, fmaf(cw.w, f5, cb))));
      float v2 = fmaf(cw.x, f3, fmaf(cw.y, f4, fmaf(cw.z, f5, fmaf(cw.w, f6, cb))));
      float v3 = fmaf(cw.x, f4, fmaf(cw.y, f5, fmaf(cw.z, f6, fmaf(cw.w, f7, cb))));
      int tt = 4 * t0;
      dstB[(tt + 0) * 72] = f2bs(silu_f(v0));
      dstB[(tt + 1) * 72] = f2bs(silu_f(v1));
      dstB[(tt + 2) * 72] = f2bs(silu_f(v2));
      dstB[(tt + 3) * 72] = f2bs(silu_f(v3));
    }
    float dtv = softplus_f(bs2f(smR1[(128 + w) * 66 + t]) + dt_bias[w]);
    smDT[w * 64 + t] = f2bs(dtv);
    float cum = -__expf(A_log[w]) * dtv;
#pragma unroll
    for (int off = 1; off < 64; off <<= 1) {
      float y = __shfl_up(cum, off, 64);
      if (t >= off) cum += y;
    }
    smCUM[w * 64 + t] = cum;
  }
  __syncthreads();

  // ---- G = C B^T via MFMA -> REGISTERS (head-independent) ----
  const int mt = w >> 1, nt0 = (w & 1) * 2;
  floatx4 g0 = (floatx4)0.f, g1 = (floatx4)0.f;
#pragma unroll
  for (int kt = 0; kt < 2; ++kt) {
    short8 a  = ld72(smC, mt * 16 + lane15, kt);
    short8 b0 = ld72(smB, nt0 * 16 + lane15, kt);
    short8 b1 = ld72(smB, (nt0 + 1) * 16 + lane15, kt);
    g0 = MF(a, b0, g0); g1 = MF(a, b1, g1);
  }
  // smB/smC reads complete before the post-P1 barrier of head 0 -> safe vs P2 writes

  float ssqAcc = 0.f;
  floatx4 accO[4][2];
#pragma unroll
  for (int m = 0; m < 4; ++m) { accO[m][0] = (floatx4)0.f; accO[m][1] = (floatx4)0.f; }

  for (int hd = 0; hd < 8; ++hd) {
    // P1: x/z head proj -> smR1 bf16 (z ch p -> row p; x ch p -> row 64+p)
    {
      int row0 = (w < 4) ? (hd * 64 + w * 16) : (512 + hd * 64 + (w - 4) * 16);
      int q = ((w < 4) ? w * 16 : 64 + (w - 4) * 16) + lane15;
      proj_tile(row0, smR1 + q * 66 + quad * 4, true);
    }
    __syncthreads();

    // P2: conv+silu x -> smX bf16 [p][s]; M built from G registers -> smM [t][s]
    {
      int p = t;                   // channel 0..63
      int ch = hd * 64 + p;
      const float4 cw = *(const float4*)(conv_w + ch * 4);
      float cb = conv_b[ch];
      const short* rowp = smR1 + (64 + p) * 66;
      short* dstX = smX + p * 72;
#pragma unroll
      for (int k = 0; k < 2; ++k) {
        int t0 = w * 2 + k;
        const short* bp = rowp + 4 * t0 - 4;
        unsigned int u0 = *(const unsigned int*)(bp + 0);
        unsigned int u1 = *(const unsigned int*)(bp + 2);
        unsigned int u2 = *(const unsigned int*)(bp + 4);
        unsigned int u3 = *(const unsigned int*)(bp + 6);
        float f1 = bhi(u0), f2 = blo(u1), f3 = bhi(u1), f4 = blo(u2);
        float f5 = bhi(u2), f6 = blo(u3), f7 = bhi(u3);
        if (t0 == 0) { f1 = 0.f; f2 = 0.f; f3 = 0.f; }
        float v0 = fmaf(cw.x, f1, fmaf(cw.y, f2, fmaf(cw.z, f3, fmaf(cw.w, f4, cb))));
        float v1 = fmaf(cw.x, f2, fmaf(cw.y, f3, fmaf(cw.z, f4, fmaf(cw.w, f5, cb))));
        float v2 = fmaf(cw.x, f3, fmaf(cw.y, f4, fmaf(cw.z, f5, fmaf(cw.w, f6, cb))));
        float v3 = fmaf(cw.x, f4, fmaf(cw.y, f5, fmaf(cw.z, f6, fmaf(cw.w, f7, cb))));
        *(unsigned int*)(dstX + 4 * t0)     = pk2(silu_f(v0), silu_f(v1));
        *(unsigned int*)(dstX + 4 * t0 + 2) = pk2(silu_f(v2), silu_f(v3));
      }
      const float* cumh = smCUM + hd * 64;
      const short* dth  = smDT + hd * 64;
#pragma unroll
      for (int j = 0; j < 2; ++j) {
        floatx4 gv = j ? g1 : g0;
        int ss = (nt0 + j) * 16 + lane15;
        float cums = cumh[ss];
        float dts  = bs2f(dth[ss]);
#pragma unroll
        for (int r = 0; r < 4; ++r) {
          int tt = mt * 16 + quad * 4 + r;
          float m = (tt >= ss) ? __expf(cumh[tt] - cums) * dts * gv[r] : 0.f;
          smM[tt * 72 + ss] = f2bs(m);
        }
      }
    }
    __syncthreads();

    // P3: Y = M X via MFMA (results stay in regs)
    floatx4 y0 = (floatx4)0.f, y1 = (floatx4)0.f;
#pragma unroll
    for (int kt = 0; kt < 2; ++kt) {
      short8 a  = ld72(smM, mt * 16 + lane15, kt);
      short8 b0 = ld72(smX, nt0 * 16 + lane15, kt);
      short8 b1 = ld72(smX, (nt0 + 1) * 16 + lane15, kt);
      y0 = MF(a, b0, y0); y1 = MF(a, b1, y1);
    }
    __syncthreads();   // all M reads done before g overwrites the M buffer

    // P4: D-term + silu(z) gating -> g[t][j] into the M buffer
    {
      float Dh = Dvec[hd];
#pragma unroll
      for (int j = 0; j < 2; ++j) {
        floatx4 yy = j ? y1 : y0;
        int p = (nt0 + j) * 16 + lane15;
        short4v xv4 = *(const short4v*)(smX + p * 72 + mt * 16 + quad * 4);
#pragma unroll
        for (int r = 0; r < 4; ++r) {
          int tr = mt * 16 + quad * 4 + r;
          float xv = bs2f(xv4[r]);
          float zv = bs2f(smR1[p * 66 + tr]);
          float g = (yy[r] + Dh * xv) * silu_f(zv);
          smg[tr * 72 + p] = f2bs(g);
        }
      }
    }
    __syncthreads();

    // P5: ssq into register accumulator + out-proj MFMA (g x Wc)
    {
      short8 gv = *(const short8*)(smg + t * 72 + w * 8);
#pragma unroll
      for (int j = 0; j < 8; ++j) { float g = bs2f(gv[j]); ssqAcc += g * g; }
    }
    __builtin_amdgcn_s_setprio(1);
#pragma unroll
    for (int kt = 0; kt < 2; ++kt) {
      short8 b0 = ldB_wc(w * 16, hd, kt);
      short8 b1 = ldB_wc((w + 8) * 16, hd, kt);
#pragma unroll
      for (int m = 0; m < 4; ++m) {
        short8 a = ld72(smg, m * 16 + lane15, kt);
        accO[m][0] = MF(a, b0, accO[m][0]);
        accO[m][1] = MF(a, b1, accO[m][1]);
      }
    }
    __builtin_amdgcn_s_setprio(0);
    // post-P1 barrier of next head guards P2's smM/smX writes vs this P5's reads
  }

  atomicAdd(&smF[t * 132 + 128], ssqAcc);
  __syncthreads();
  if (tid < 64)
    smF[tid * 132 + 129] = rsqrtf(smF[tid * 132 + 128] * (1.f / 512.f) + 1e-5f);
  __syncthreads();

  // ---- epilogue: RMS scale, direct C-layout global writes ----
#pragma unroll
  for (int m = 0; m < 4; ++m) {
#pragma unroll
    for (int n = 0; n < 2; ++n) {
      int o = (w + n * 8) * 16 + lane15;
#pragma unroll
      for (int r = 0; r < 4; ++r) {
        int tt = m * 16 + quad * 4 + r;
        float val = accO[m][n][r] * smF[tt * 132 + 129];
        long rowg = (DIR == 0) ? ((long)s * 64 + tt)
                               : ((long)(s >> 6) * 4096 + (long)tt * 64 + (s & 63));
        long gi = rowg * 256 + o;
        if (DIR == 0) out[gi] = fc_b[o] + val;
        else          out[gi] += val;
      }
    }
  }
}

extern "C" void kernel_launch(void* const* d_in, const int* in_sizes, int n_in,
                              void* d_out, int out_size, void* d_ws, size_t ws_size,
                              hipStream_t stream) {
  const float* x          = (const float*)d_in[0];
  const float* mh_in_w    = (const float*)d_in[1];
  const float* mh_conv_w  = (const float*)d_in[2];
  const float* mh_conv_b  = (const float*)d_in[3];
  const float* mh_dt_bias = (const float*)d_in[4];
  const float* mh_A_log   = (const float*)d_in[5];
  const float* mh_D       = (const float*)d_in[6];
  const float* mh_norm_w  = (const float*)d_in[7];
  const float* mh_out_w   = (const float*)d_in[8];
  const float* mv_in_w    = (const float*)d_in[9];
  const float* mv_conv_w  = (const float*)d_in[10];
  const float* mv_conv_b  = (const float*)d_in[11];
  const float* mv_dt_bias = (const float*)d_in[12];
  const float* mv_A_log   = (const float*)d_in[13];
  const float* mv_D       = (const float*)d_in[14];
  const float* mv_norm_w  = (const float*)d_in[15];
  const float* mv_out_w   = (const float*)d_in[16];
  const float* fc_w       = (const float*)d_in[17];
  const float* fc_b       = (const float*)d_in[18];
  float* out = (float*)d_out;

  __hip_bfloat16* Wcb  = (__hip_bfloat16*)d_ws;                       // 2*131072 bf16
  __hip_bfloat16* inwb = (__hip_bfloat16*)((char*)d_ws + 524288);     // 2*1168*256 bf16

  setup_weights<<<804, 256, 0, stream>>>(fc_w, mh_out_w, mh_norm_w, mv_out_w, mv_norm_w,
                                         mh_in_w, mv_in_w, Wcb, inwb);
  mamba_dir_kernel<0><<<512, NTH, 0, stream>>>(x, inwb, mh_conv_w, mh_conv_b,
      mh_dt_bias, mh_A_log, mh_D, Wcb, fc_b, out);
  mamba_dir_kernel<1><<<512, NTH, 0, stream>>>(x, inwb + 299008, mv_conv_w, mv_conv_b,
      mv_dt_bias, mv_A_log, mv_D, Wcb + 131072, fc_b, out);
}